// Round 12
// baseline (708.828 us; speedup 1.0000x reference)
//
#include <hip/hip_runtime.h>
#include <hip/hip_bf16.h>

// Problem constants (fixed by reference): N=262144 rows, D=64, K=512 codes.
#define N_ROWS 262144
#define DIM 64
#define KC 512
#define KHALF 256                      // codes per half
#define BLK 512                        // threads/block; 8 waves
#define RPT 2                          // rows per thread
#define LDS_FLOATS (KHALF * DIM + KHALF)  // half codebook + half esq = 66560 B

// d_out layout — FLOAT32 (verified passing):
//   out[0]                      = loss
//   out[1 .. 1+N*D)             = quantized [N,64] row-major
//   out[1+N*D .. 1+N*D+N)       = float(encoding_indices)
//
// Numerics replicated exactly (indices must match np.argmin of f32 dists):
//   x_sq, e_sq : numpy pairwise sum, n=64 => 8-accumulator striped scheme
//   dot        : sequential fused-FMA chain, ascending j (OpenBLAS kernel)
//   d          : fl( fl(x_sq + e_sq_k) - 2*dot_k ), contraction off
//   argmin     : strict <, first-min-wins (k ascending; A-half wins ties)
//
// Pipe model (R7/R8/R10/R11 evidence): per-CU LDS broadcast demand and
// per-SIMD FMA demand are both ~109us. R7 (4 waves/SIMD): overlap works,
// wall = LDS. R8 (2 waves/SIMD): DS and VALU SERIALIZE per wave => 164+109
// = 276us. R11 (global pipe-split): vmcnt latency exposure, 314us. The
// only fix is occupancy: 4 waves/SIMD with RPT=2.
// R12: SPLIT CODEBOOK. Each block stages HALF the codebook (65KB LDS =>
// 2 blocks/CU => 16 waves = 4/SIMD), computes partial argmin over its 256
// codes, writes (best, idx) per row to workspace. combine_kernel picks the
// winner (A-half on ties => first-min-wins), gathers quantized rows from
// the L2-hot global codebook, accumulates the loss. LDS work per CU is
// invariant; TLP now hides VALU under LDS (R7-proven at 4 waves/SIMD).

// numpy pairwise sum of squares for n=64 (scalar path, PW_BLOCKSIZE=128).
__device__ __forceinline__ float np_sumsq64(const float* a) {
#pragma clang fp contract(off)
    float r[8];
#pragma unroll
    for (int j = 0; j < 8; ++j) r[j] = a[j] * a[j];
#pragma unroll
    for (int i = 8; i < 64; i += 8)
#pragma unroll
        for (int j = 0; j < 8; ++j) r[j] = r[j] + a[i + j] * a[i + j];
    return ((r[0] + r[1]) + (r[2] + r[3])) + ((r[4] + r[5]) + (r[6] + r[7]));
}

// ---- kernel 1: e_sq_k with numpy bit-exact summation ----
__global__ void esq_kernel(const float* __restrict__ cb, float* __restrict__ esq) {
    int k = blockIdx.x * blockDim.x + threadIdx.x;
    if (k < KC) esq[k] = np_sumsq64(cb + k * DIM);
}

// ---- kernel 2: partial VQ — half codebook in LDS, 2 blocks/CU ----
__global__ __launch_bounds__(BLK)
__attribute__((amdgpu_waves_per_eu(4, 4)))   // 4 waves/SIMD; 128-VGPR budget
void vq_partial(
    const float* __restrict__ x, const float* __restrict__ cb,
    const float* __restrict__ esq_g,
    float* __restrict__ pbest, float* __restrict__ pidx)
{
    extern __shared__ float smem[];
    float* cbs  = smem;                  // [256*64] half codebook
    float* esql = smem + KHALF * DIM;    // [256]

    const int bid   = blockIdx.x;        // 0..511
    const int half  = bid & 1;           // interleave halves across XCDs
    const int chunk = bid >> 1;          // 0..255 row chunk
    const int tid   = threadIdx.x;
    const int lane  = tid & 63;
    const int row0  = chunk * (BLK * RPT) + tid;   // rows row0, row0+BLK
    const int row1  = row0 + BLK;
    const int kbase = half * KHALF;

    // ---- cooperative stage: 64KB half-codebook + 1KB esq, coalesced ----
    {
        const float4* g4 = reinterpret_cast<const float4*>(cb + (size_t)kbase * DIM);
        float4*       s4 = reinterpret_cast<float4*>(cbs);
#pragma unroll
        for (int i = 0; i < (KHALF * DIM / 4) / BLK; ++i)   // 8 iters
            s4[tid + i * BLK] = g4[tid + i * BLK];
        if (tid < KHALF) esql[tid] = esq_g[kbase + tid];
    }

    // Two rows into 128 VGPRs — overlaps staging latency.
    float xr0[DIM], xr1[DIM];
    {
        const float4* xv0 = reinterpret_cast<const float4*>(x + (size_t)row0 * DIM);
        const float4* xv1 = reinterpret_cast<const float4*>(x + (size_t)row1 * DIM);
#pragma unroll
        for (int j = 0; j < DIM / 4; ++j) {
            float4 v0 = xv0[j], v1 = xv1[j];
            xr0[4 * j + 0] = v0.x; xr0[4 * j + 1] = v0.y;
            xr0[4 * j + 2] = v0.z; xr0[4 * j + 3] = v0.w;
            xr1[4 * j + 0] = v1.x; xr1[4 * j + 1] = v1.y;
            xr1[4 * j + 2] = v1.z; xr1[4 * j + 3] = v1.w;
        }
    }

    // numpy-exact ||x||^2 per row.
    const float xsq0 = np_sumsq64(xr0);
    const float xsq1 = np_sumsq64(xr1);

    __syncthreads();   // staging complete

    // 2 codes x 2 rows per iter = 4 independent sequential fused-FMA chains
    // (bit-identical to R8's chains; only 128 iterations of local codes).
    float best0 = 3.4e38f, best1 = 3.4e38f;
    int bidx0 = 0, bidx1 = 0;
#pragma unroll 1
    for (int k = 0; k < KHALF; k += 2) {
        const float4* ea = reinterpret_cast<const float4*>(cbs + k * DIM);
        const float4* eb = ea + DIM / 4;
        float dot00 = 0.f, dot01 = 0.f, dot10 = 0.f, dot11 = 0.f;
#pragma unroll
        for (int c = 0; c < DIM / 4; ++c) {
            const float4 a = ea[c];
            const float4 b = eb[c];
            dot00 = fmaf(xr0[4 * c + 0], a.x, dot00);
            dot01 = fmaf(xr0[4 * c + 0], b.x, dot01);
            dot10 = fmaf(xr1[4 * c + 0], a.x, dot10);
            dot11 = fmaf(xr1[4 * c + 0], b.x, dot11);
            dot00 = fmaf(xr0[4 * c + 1], a.y, dot00);
            dot01 = fmaf(xr0[4 * c + 1], b.y, dot01);
            dot10 = fmaf(xr1[4 * c + 1], a.y, dot10);
            dot11 = fmaf(xr1[4 * c + 1], b.y, dot11);
            dot00 = fmaf(xr0[4 * c + 2], a.z, dot00);
            dot01 = fmaf(xr0[4 * c + 2], b.z, dot01);
            dot10 = fmaf(xr1[4 * c + 2], a.z, dot10);
            dot11 = fmaf(xr1[4 * c + 2], b.z, dot11);
            dot00 = fmaf(xr0[4 * c + 3], a.w, dot00);
            dot01 = fmaf(xr0[4 * c + 3], b.w, dot01);
            dot10 = fmaf(xr1[4 * c + 3], a.w, dot10);
            dot11 = fmaf(xr1[4 * c + 3], b.w, dot11);
        }
        float d00, d01, d10, d11;
        {
#pragma clang fp contract(off)
            const float e0 = esql[k + 0], e1 = esql[k + 1];
            d00 = (xsq0 + e0) - 2.0f * dot00;  // 2*dot exact; each op rounds
            d01 = (xsq0 + e1) - 2.0f * dot01;
            d10 = (xsq1 + e0) - 2.0f * dot10;
            d11 = (xsq1 + e1) - 2.0f * dot11;
        }
        // strict <, ascending k: first-min-wins preserved (per row).
        if (d00 < best0) { best0 = d00; bidx0 = k + 0; }
        if (d01 < best0) { best0 = d01; bidx0 = k + 1; }
        if (d10 < best1) { best1 = d10; bidx1 = k + 0; }
        if (d11 < best1) { best1 = d11; bidx1 = k + 1; }
    }

    // ---- write partials (coalesced) ----
    const size_t po = (size_t)half * N_ROWS;
    pbest[po + row0] = best0;
    pbest[po + row1] = best1;
    pidx [po + row0] = (float)(kbase + bidx0);
    pidx [po + row1] = (float)(kbase + bidx1);
}

// ---- kernel 3: combine halves, gather quantized, loss ----
__global__ __launch_bounds__(256) void combine_kernel(
    const float* __restrict__ cb,
    const float* __restrict__ pbest, const float* __restrict__ pidx,
    float* __restrict__ out, float* __restrict__ loss_acc)
{
    const int r    = blockIdx.x * 256 + threadIdx.x;
    const int lane = threadIdx.x & 63;

    const float bA = pbest[r], bB = pbest[N_ROWS + r];
    float best = bA;
    int   bidx = (int)pidx[r];
    if (bB < bA) { best = bB; bidx = (int)pidx[N_ROWS + r]; }  // strict <: A wins ties

    // wave-cooperative coalesced gather+store (R3-proven pattern),
    // codebook rows from global (128KB, L2-hot).
    const size_t wave_r0 = (size_t)r - lane;
#pragma unroll 4
    for (int l = 0; l < 64; ++l) {
        const int idx = __shfl(bidx, l, 64);
        out[1 + (wave_r0 + l) * DIM + lane] = cb[(size_t)idx * DIM + lane];
    }

    out[1 + (size_t)N_ROWS * DIM + r] = (float)bidx;  // coalesced

    // loss contribution: ||x - e||^2 = best (noise ~1e-5, threshold ~2%)
    float lrow = best;
#pragma unroll
    for (int off = 32; off > 0; off >>= 1) lrow += __shfl_down(lrow, off, 64);
    if (lane == 0) atomicAdd(loss_acc, lrow);
}

// ---- kernel 4: finalize loss ----
__global__ void fin_kernel(const float* __restrict__ loss_acc,
                           float* __restrict__ out) {
    if (threadIdx.x == 0) {
        float mean_sq = (*loss_acc) / (float)((size_t)N_ROWS * DIM);
        out[0] = 1.25f * mean_sq;  // q_loss + COMMITMENT_COST * e_loss
    }
}

extern "C" void kernel_launch(void* const* d_in, const int* in_sizes, int n_in,
                              void* d_out, int out_size, void* d_ws, size_t ws_size,
                              hipStream_t stream) {
    const float* x  = (const float*)d_in[0];
    const float* cb = (const float*)d_in[1];
    float* out = (float*)d_out;

    // workspace layout
    float* loss_acc = (float*)d_ws;                          // 4 B
    float* esq      = (float*)((char*)d_ws + 256);           // 512 f
    float* pbest    = (float*)((char*)d_ws + 4096);          // 2*N f = 2 MB
    float* pidx     = pbest + 2 * (size_t)N_ROWS;            // 2*N f = 2 MB

    hipMemsetAsync(d_ws, 0, 4, stream);                      // zero loss accumulator
    esq_kernel<<<2, 256, 0, stream>>>(cb, esq);
    vq_partial<<<2 * (N_ROWS / (BLK * RPT)), BLK, LDS_FLOATS * sizeof(float), stream>>>(
        x, cb, esq, pbest, pidx);
    combine_kernel<<<N_ROWS / 256, 256, 0, stream>>>(cb, pbest, pidx, out, loss_acc);
    fin_kernel<<<1, 64, 0, stream>>>(loss_acc, out);
}

// Round 13
// 496.435 us; speedup vs baseline: 1.4278x; 1.4278x over previous
//
#include <hip/hip_runtime.h>
#include <hip/hip_bf16.h>

// Problem constants (fixed by reference): N=262144 rows, D=64, K=512 codes.
#define N_ROWS 262144
#define DIM 64
#define KC 512
#define BLK 256                        // threads/block; 4 waves = 1/SIMD, 1 block/CU
#define RPT 4                          // rows per thread
#define LDS_FLOATS (KC * DIM + KC)     // codebook + esq = 33280 floats = 133120 B

// d_out layout — FLOAT32 (verified passing):
//   out[0]                      = loss
//   out[1 .. 1+N*D)             = quantized [N,64] row-major
//   out[1+N*D .. 1+N*D+N)       = float(encoding_indices)
//
// Numerics replicated exactly (indices must match np.argmin of f32 dists):
//   x_sq, e_sq : numpy pairwise sum, n=64 => 8-accumulator striped scheme
//   dot        : sequential fused-FMA chain, ascending j (OpenBLAS kernel)
//   d          : fl( fl(x_sq + e_sq_k) - 2*dot_k ), contraction off
//   argmin     : strict <, first-min-wins (k ascending)
//
// R12 post-mortem: waves_per_eu(4,4) => 128-VGPR cap => allocator evicted
// the rows and REMATERIALIZED them from global in the k-loop; x (62MB) >
// L2 (32MB) => FETCH exploded to 1.22GB, 628us. Proven: RPT=2 row
// residency (~160 VGPR) and 4 waves/SIMD are mutually exclusive.
// Constraint algebra (m69 steps 64/128/256): LDS-read demand ∝ 1/RPT;
// row VGPRs = 64*RPT; waves ∝ 1/VGPR. Unexplored corner: RPT=4 at 1
// wave/SIMD with the FULL 512-VGPR budget.
// R13: BLK=256 (4 waves, 1 block/CU, grid=256), RPT=4, waves_per_eu(1,1).
// Per k-pair iter: 512 FMAs (1024 issue-cyc) vs 32 uniform ds_read_b128
// (192 LDS-pipe cyc) = 5:1 -> in-order barrier-free DS reads pipeline
// under the FMA burst even with zero TLP. Per-SIMD FMA time = 109us
// (the floor); LDS demand 82us/CU hides. Rows ~256 VGPR + temps ~ 310,
// under the 450 no-spill ceiling (m08).

// numpy pairwise sum of squares for n=64 (scalar path, PW_BLOCKSIZE=128).
__device__ __forceinline__ float np_sumsq64(const float* a) {
#pragma clang fp contract(off)
    float r[8];
#pragma unroll
    for (int j = 0; j < 8; ++j) r[j] = a[j] * a[j];
#pragma unroll
    for (int i = 8; i < 64; i += 8)
#pragma unroll
        for (int j = 0; j < 8; ++j) r[j] = r[j] + a[i + j] * a[i + j];
    return ((r[0] + r[1]) + (r[2] + r[3])) + ((r[4] + r[5]) + (r[6] + r[7]));
}

// ---- kernel 1: e_sq_k with numpy bit-exact summation ----
__global__ void esq_kernel(const float* __restrict__ cb, float* __restrict__ esq) {
    int k = blockIdx.x * blockDim.x + threadIdx.x;
    if (k < KC) esq[k] = np_sumsq64(cb + k * DIM);
}

// ---- kernel 2: main VQ — FOUR rows per thread, codebook in LDS ----
__global__ __launch_bounds__(BLK)
__attribute__((amdgpu_waves_per_eu(1, 1)))   // 1 wave/SIMD target: full VGPR budget
void vq_kernel(
    const float* __restrict__ x, const float* __restrict__ cb,
    const float* __restrict__ esq_g, float* __restrict__ out,
    float* __restrict__ loss_acc)
{
    extern __shared__ float smem[];
    float* cbs  = smem;             // [512*64] codebook, k-major (global layout)
    float* esql = smem + KC * DIM;  // [512]

    const int tid  = threadIdx.x;
    const int lane = tid & 63;
    const int rbase = blockIdx.x * (BLK * RPT) + tid;  // rows rbase + s*BLK, s=0..3

    // ---- cooperative stage: 128KB codebook + 2KB esq, fully coalesced ----
    {
        const float4* g4 = reinterpret_cast<const float4*>(cb);
        float4*       s4 = reinterpret_cast<float4*>(cbs);
#pragma unroll
        for (int i = 0; i < (KC * DIM / 4) / BLK; ++i)   // 32 iters
            s4[tid + i * BLK] = g4[tid + i * BLK];
        esql[tid]       = esq_g[tid];
        esql[BLK + tid] = esq_g[BLK + tid];
    }

    // Four rows into 256 VGPRs — overlaps staging latency.
    float xr[RPT][DIM];
#pragma unroll
    for (int s = 0; s < RPT; ++s) {
        const float4* xv = reinterpret_cast<const float4*>(
            x + (size_t)(rbase + s * BLK) * DIM);
#pragma unroll
        for (int j = 0; j < DIM / 4; ++j) {
            float4 v = xv[j];
            xr[s][4 * j + 0] = v.x; xr[s][4 * j + 1] = v.y;
            xr[s][4 * j + 2] = v.z; xr[s][4 * j + 3] = v.w;
        }
    }

    // numpy-exact ||x||^2 per row.
    float xsq[RPT];
#pragma unroll
    for (int s = 0; s < RPT; ++s) xsq[s] = np_sumsq64(xr[s]);

    __syncthreads();   // staging complete

    // 2 codes x 4 rows per iter = 8 independent sequential fused-FMA chains
    // (dep distance 8 instr x 2 cyc = 16 >> 4-cyc FMA latency). Each 16B
    // LDS broadcast read feeds 16 FMAs.
    float best[RPT];
    int   bidx[RPT];
#pragma unroll
    for (int s = 0; s < RPT; ++s) { best[s] = 3.4e38f; bidx[s] = 0; }

#pragma unroll 1
    for (int k = 0; k < KC; k += 2) {
        const float4* ea = reinterpret_cast<const float4*>(cbs + k * DIM);
        const float4* eb = ea + DIM / 4;
        float dotA[RPT] = {0.f, 0.f, 0.f, 0.f};   // vs code k
        float dotB[RPT] = {0.f, 0.f, 0.f, 0.f};   // vs code k+1
#pragma unroll
        for (int c = 0; c < DIM / 4; ++c) {
            const float4 a = ea[c];
            const float4 b = eb[c];
#pragma unroll
            for (int s = 0; s < RPT; ++s) {
                // ascending j = 4c..4c+3 within each chain (bit-exact order)
                dotA[s] = fmaf(xr[s][4 * c + 0], a.x, dotA[s]);
                dotB[s] = fmaf(xr[s][4 * c + 0], b.x, dotB[s]);
                dotA[s] = fmaf(xr[s][4 * c + 1], a.y, dotA[s]);
                dotB[s] = fmaf(xr[s][4 * c + 1], b.y, dotB[s]);
                dotA[s] = fmaf(xr[s][4 * c + 2], a.z, dotA[s]);
                dotB[s] = fmaf(xr[s][4 * c + 2], b.z, dotB[s]);
                dotA[s] = fmaf(xr[s][4 * c + 3], a.w, dotA[s]);
                dotB[s] = fmaf(xr[s][4 * c + 3], b.w, dotB[s]);
            }
        }
        {
#pragma clang fp contract(off)
            const float e0 = esql[k + 0], e1 = esql[k + 1];
#pragma unroll
            for (int s = 0; s < RPT; ++s) {
                const float dA = (xsq[s] + e0) - 2.0f * dotA[s];  // each op rounds
                const float dB = (xsq[s] + e1) - 2.0f * dotB[s];
                // strict <, ascending k: first-min-wins preserved (per row).
                if (dA < best[s]) { best[s] = dA; bidx[s] = k + 0; }
                if (dB < best[s]) { best[s] = dB; bidx[s] = k + 1; }
            }
        }
    }

    // ---- wave-cooperative coalesced epilogue (R3-proven), per row-set ----
    // LDS gather: lane l reads cbs[idx*64 + l] -> 2-way bank aliasing = free.
#pragma unroll
    for (int s = 0; s < RPT; ++s) {
        const size_t wrow = (size_t)(rbase + s * BLK) - lane;
#pragma unroll 4
        for (int l = 0; l < 64; ++l) {
            const int idx = __shfl(bidx[s], l, 64);
            out[1 + (wrow + l) * DIM + lane] = cbs[idx * DIM + lane];
        }
        out[1 + (size_t)N_ROWS * DIM + (rbase + s * BLK)] = (float)bidx[s];
    }

    // loss contribution: sum of 4 rows' ||x - e||^2 (noise ~1e-5, thr ~2%)
    float lrow = (best[0] + best[1]) + (best[2] + best[3]);
#pragma unroll
    for (int off = 32; off > 0; off >>= 1) lrow += __shfl_down(lrow, off, 64);
    if (lane == 0) atomicAdd(loss_acc, lrow);
}

// ---- kernel 3: finalize loss ----
__global__ void fin_kernel(const float* __restrict__ loss_acc,
                           float* __restrict__ out) {
    if (threadIdx.x == 0) {
        float mean_sq = (*loss_acc) / (float)((size_t)N_ROWS * DIM);
        out[0] = 1.25f * mean_sq;  // q_loss + COMMITMENT_COST * e_loss
    }
}

extern "C" void kernel_launch(void* const* d_in, const int* in_sizes, int n_in,
                              void* d_out, int out_size, void* d_ws, size_t ws_size,
                              hipStream_t stream) {
    const float* x  = (const float*)d_in[0];
    const float* cb = (const float*)d_in[1];
    float* out = (float*)d_out;

    float* loss_acc = (float*)d_ws;                 // 4 B accumulator
    float* esq      = (float*)((char*)d_ws + 256);  // 512 floats

    hipMemsetAsync(d_ws, 0, 4, stream);             // zero loss accumulator
    esq_kernel<<<2, 256, 0, stream>>>(cb, esq);
    vq_kernel<<<N_ROWS / (BLK * RPT), BLK, LDS_FLOATS * sizeof(float), stream>>>(
        x, cb, esq, out, loss_acc);
    fin_kernel<<<1, 64, 0, stream>>>(loss_acc, out);
}